// Round 14
// baseline (64.221 us; speedup 1.0000x reference)
//
#include <hip/hip_runtime.h>
#include <cmath>

#define BB 64
#define TT 512
#define CC 1000
#define SS 32
#define COR 4
#define NPROB (BB + BB*COR)   // 320
#define NEGV (-1e30f)
#define LOG2E 1.4426950408889634f
#define LN2 0.6931471805599453f
#define BIAS 50               // renorm target exponent: needed-max -> 2^BIAS
#define SHIFT 16.0f           // constant lse shift (replaces wave max; |w|<=8)

// ---------------------------------------------------------------------------
// DPP helpers (VALU-pipe cross-lane). 0x138 = wave_shr:1 (HW-verified r3-r13).
// Reduction tree row_shr:1/2/4/8 + row_bcast:15/31 -> lane 63 (HW-verified).
// ---------------------------------------------------------------------------
__device__ __forceinline__ float dpp_shr1_fill(float x, float fill) {
    int r = __builtin_amdgcn_update_dpp(__builtin_bit_cast(int, fill),
                                        __builtin_bit_cast(int, x),
                                        0x138, 0xf, 0xf, false);   // lane0 <- fill
    return __builtin_bit_cast(float, r);
}
__device__ __forceinline__ float dpp_shr1_z(float x) {
    int r = __builtin_amdgcn_update_dpp(0, __builtin_bit_cast(int, x),
                                        0x138, 0xf, 0xf, true);    // lane0 <- 0
    return __builtin_bit_cast(float, r);
}
template<int CTRL>
__device__ __forceinline__ float dpp_maxf(float m) {   // 0-fill ok: A >= 0
    int r = __builtin_amdgcn_update_dpp(0, __builtin_bit_cast(int, m),
                                        CTRL, 0xf, 0xf, true);
    return fmaxf(m, __builtin_bit_cast(float, r));
}
template<int CTRL>
__device__ __forceinline__ float dpp_addf(float s) {
    int r = __builtin_amdgcn_update_dpp(0, __builtin_bit_cast(int, s),
                                        CTRL, 0xf, 0xf, true);     // invalid -> +0
    return s + __builtin_bit_cast(float, r);
}
__device__ __forceinline__ float rdlane(float x, int lane) {
    return __builtin_bit_cast(float, __builtin_amdgcn_readlane(__builtin_bit_cast(int, x), lane));
}
// exact full-wave sum, result broadcast via readlane 63
__device__ __forceinline__ float wave_sum(float s) {
    s = dpp_addf<0x111>(s);
    s = dpp_addf<0x112>(s);
    s = dpp_addf<0x114>(s);
    s = dpp_addf<0x118>(s);
    s = dpp_addf<0x142>(s);
    s = dpp_addf<0x143>(s);
    return rdlane(s, 63);
}

// Renorm vs max over NEEDED lanes (lane < nl), all-VALU (~40cy).
// Scales so needed-max exponent == BIAS; accumulates true exponent in off.
__device__ __forceinline__ void renorm(float &A, float &a0, int &off,
                                       int lane, int nl) {
    float m = (lane < nl) ? A : 0.f;
    m = dpp_maxf<0x111>(m);
    m = dpp_maxf<0x112>(m);
    m = dpp_maxf<0x114>(m);
    m = dpp_maxf<0x118>(m);
    m = dpp_maxf<0x142>(m);
    m = dpp_maxf<0x143>(m);
    int mb = __builtin_amdgcn_readlane(__builtin_bit_cast(int, m), 63);
    int e = ((mb >> 23) & 0xff) - 127 - BIAS;
    e = (mb & 0x7fffffff) ? e : 0;       // m==0 guard
    A  = ldexpf(A,  -e);
    a0 = ldexpf(a0, -e);
    off += e;
}

// ---------------------------------------------------------------------------
// Gather kernel (r10-proven, byte-identical): per preds row [b,t,:]:
// coalesced float4 read; constant-shift exp2 sum (exps overlap loads);
// DPP wave_sum; write LINEAR normalized probs labels[pid][t][k] (fp32) and
// blankE[b][t].
// ---------------------------------------------------------------------------
__global__ __launch_bounds__(256) void gather_kernel(const float* __restrict__ preds,
                                                     const int* __restrict__ text,
                                                     const int* __restrict__ stext,
                                                     float* __restrict__ labels,
                                                     float* __restrict__ blankE) {
    int gw = (blockIdx.x * blockDim.x + threadIdx.x) >> 6;   // row = b*512+t
    int lane = threadIdx.x & 63;
    if (gw >= BB * TT) return;
    int b = gw >> 9;
    int t = gw & (TT - 1);
    const float* row = preds + (size_t)gw * CC;
    const float4* row4 = (const float4*)row;
    float s = 0.f;
#pragma unroll
    for (int i = 0; i < 4; ++i) {
        int idx = lane + i * 64;
        float4 x = (idx < 250) ? row4[idx] : make_float4(NEGV, NEGV, NEGV, NEGV);
        s += exp2f(fmaf(x.x, LOG2E, -SHIFT));
        s += exp2f(fmaf(x.y, LOG2E, -SHIFT));
        s += exp2f(fmaf(x.z, LOG2E, -SHIFT));
        s += exp2f(fmaf(x.w, LOG2E, -SHIFT));
    }
    s = wave_sum(s);
    float lse2 = SHIFT + log2f(s);           // wave-uniform log2(sum exp2)

    if (lane == 0) blankE[gw] = exp2f(fmaf(row[0], LOG2E, -lse2));

#pragma unroll
    for (int it = 0; it < 3; ++it) {
        int g = lane + it * 64;
        if (g < 5 * SS) {
            int pp = g >> 5, k = g & 31;
            int cls, pid;
            if (pp == 0) { cls = text[b * SS + k]; pid = b; }
            else { int i = b * COR + (pp - 1); cls = stext[i * SS + k]; pid = BB + i; }
            labels[((size_t)pid * TT + t) * SS + k] = exp2f(fmaf(row[cls], LOG2E, -lse2));
        }
    }
}

// ---------------------------------------------------------------------------
// Linear-domain CTC (r13 + shortened critical path). Lane s owns extended
// position s+1; position 0 (leading blank) is the wave-uniform scalar a0
// (DPP fill operand). Per-step update:
//   A' = fma(p2, e2, (A + p1) * ev)  with e2 = use2 ? ev : 0 hoisted OFF the
// chain (use2 is per-lane constant, ev is buffered) -> critical path is
// dpp -> add -> mul -> fma (4 deps; dpp2 runs parallel to add/mul) vs r13's
// dpp -> dpp -> cndmask -> add -> mul (5 deps).
// CH=32 prefetch covers ~600cy L3 latency. Renorm every 8 steps, BIAS=50.
// loss = -ln2 * (log2(A[2len-1] + A[2len-2]) + off)  (emits pre-normalized).
// ---------------------------------------------------------------------------
__global__ __launch_bounds__(64) void ctc_lin_kernel(const float* __restrict__ labels,
                                                     const float* __restrict__ blankE,
                                                     const int* __restrict__ text,
                                                     const int* __restrict__ length,
                                                     const int* __restrict__ stext,
                                                     const int* __restrict__ slength,
                                                     float* __restrict__ lm,
                                                     float* __restrict__ ls) {
    const int p = blockIdx.x;
    const int lane = threadIdx.x;

    int b, len;
    const int* tgt;
    if (p < BB) { b = p;        tgt = text  + (size_t)p * SS; len = length[p]; }
    else { int i = p - BB; b = i / COR; tgt = stext + (size_t)i * SS; len = slength[i]; }

    const bool evenl = !(lane & 1);
    const int k = lane >> 1;
    bool use2 = false;
    if (evenl && lane >= 2) use2 = (tgt[k] != tgt[k - 1]);

    const float* bbase = blankE + (size_t)b * TT;
    const float* lbase = labels + (size_t)p * TT * SS + k;     // even lanes
    const int i2 = 2 * len;                  // needed lanes: [0, i2)

    constexpr int CH = 32;
    constexpr int NCH = TT / CH;             // 16
    float eA[CH], eB[CH], bA[CH], bB[CH];

    auto loadChunk = [&](float (&ee)[CH], float (&bv)[CH], int c) {
        if (evenl) {
#pragma unroll
            for (int j = 0; j < CH; ++j)
                ee[j] = lbase[(size_t)(c * CH + j) * SS];
        }
        const float4* b4 = (const float4*)(bbase + c * CH);
#pragma unroll
        for (int q = 0; q < CH / 4; ++q) {
            float4 y = b4[q];
            bv[q*4+0] = y.x; bv[q*4+1] = y.y; bv[q*4+2] = y.z; bv[q*4+3] = y.w;
        }
    };

    float A, a0;
    int off = 0;

#define RUNCH(EE, BV, START)                                    \
    _Pragma("unroll")                                           \
    for (int j = (START); j < CH; ++j) {                        \
        float ev = evenl ? EE[j] : BV[j];                       \
        float e2 = use2 ? ev : 0.f;      /* off-chain select */ \
        float p1 = dpp_shr1_fill(A, a0);                        \
        float p2 = dpp_shr1_z(p1);                              \
        A = fmaf(p2, e2, (A + p1) * ev);                        \
        a0 *= BV[j];                                            \
        if ((j & 7) == 7) renorm(A, a0, off, lane, i2);         \
    }

    // prologue: chunk 0 (t=0 is init), chunk 1 prefetched
    loadChunk(eA, bA, 0);
    loadChunk(eB, bB, 1);
    A  = (lane == 0) ? eA[0] : 0.f;          // alpha0[pos1] = emit(y1); lane0 even
    a0 = bA[0];                              // alpha0[pos0] = emit(blank)
    RUNCH(eA, bA, 1)

    for (int c = 1; c < NCH; c += 2) {
        if (c + 1 < NCH) loadChunk(eA, bA, c + 1);
        RUNCH(eB, bB, 0)
        if (c + 1 < NCH) {
            if (c + 2 < NCH) loadChunk(eB, bB, c + 2);
            RUNCH(eA, bA, 0)
        }
    }
#undef RUNCH

    // final: alpha[2len] at lane 2len-1, alpha[2len-1] at lane 2len-2
    float vhi = rdlane(A, i2 - 1);
    float vlo = rdlane(A, i2 - 2);
    float loss = -LN2 * (log2f(vhi + vlo) + (float)off);

    if (lane == 0) {
        if (p < BB) lm[p] = loss;
        else        ls[p - BB] = loss;
    }
}

// ---------------------------------------------------------------------------
// Fallback path (only if ws too small) — round-3 log-domain kernels (proven).
// ---------------------------------------------------------------------------
__global__ __launch_bounds__(256) void lse_kernel(const float* __restrict__ preds,
                                                  float* __restrict__ lse) {
    int wave = (blockIdx.x * blockDim.x + threadIdx.x) >> 6;
    int lane = threadIdx.x & 63;
    if (wave >= BB * TT) return;
    const float4* row = (const float4*)(preds + (size_t)wave * CC);
    float v[16];
#pragma unroll
    for (int i = 0; i < 4; ++i) {
        int idx = lane + i * 64;
        float4 x = (idx < 250) ? row[idx] : make_float4(NEGV, NEGV, NEGV, NEGV);
        v[i*4+0] = x.x; v[i*4+1] = x.y; v[i*4+2] = x.z; v[i*4+3] = x.w;
    }
    float m = v[0];
#pragma unroll
    for (int i = 1; i < 16; ++i) m = fmaxf(m, v[i]);
#pragma unroll
    for (int off = 32; off; off >>= 1) m = fmaxf(m, __shfl_xor(m, off));
    float s = 0.f;
#pragma unroll
    for (int i = 0; i < 16; ++i) s += exp2f((v[i] - m) * LOG2E);
#pragma unroll
    for (int off = 32; off; off >>= 1) s += __shfl_xor(s, off);
    if (lane == 0) lse[wave] = m + log2f(s) * LN2;
}

__global__ __launch_bounds__(64) void ctc_kernel(const float* __restrict__ preds,
                                                 const float* __restrict__ lse,
                                                 const int* __restrict__ text,
                                                 const int* __restrict__ length,
                                                 const int* __restrict__ stext,
                                                 const int* __restrict__ slength,
                                                 float* __restrict__ lm,
                                                 float* __restrict__ ls) {
    const int p = blockIdx.x;
    const int lane = threadIdx.x;
    int b, len;
    const int* tgt;
    if (p < BB) { b = p;        tgt = text  + (size_t)p * SS; len = length[p]; }
    else { int i = p - BB; b = i / COR; tgt = stext + (size_t)i * SS; len = slength[i]; }
    const int s = lane;
    int cls = (s & 1) ? tgt[(s - 1) >> 1] : 0;
    bool use2 = false;
    if ((s & 1) && s >= 3) use2 = (cls != tgt[(s - 3) >> 1]);
    const float* pcls = preds + (size_t)b * TT * CC + cls;
    const float* lrow = lse + (size_t)b * TT;
    float ksum = 0.f;
#pragma unroll
    for (int i = 0; i < TT / 64; ++i) ksum += lrow[lane + i * 64];
#pragma unroll
    for (int off = 32; off; off >>= 1) ksum += __shfl_xor(ksum, off);
    float a, a64 = NEGV;
    constexpr int CH = 8;
    constexpr int NCH = TT / CH;
    float pvA[CH], pvB[CH];
    auto loadChunk = [&](float (&pv)[CH], int c) {
#pragma unroll
        for (int j = 0; j < CH; ++j) pv[j] = pcls[(size_t)(c * CH + j) * CC];
    };
    auto step = [&](float ev) {
        float p1 = dpp_shr1_fill(a, NEGV);
        float p2 = dpp_shr1_fill(p1, NEGV);
        float x2 = use2 ? p2 : NEGV;
        float m3 = fmaxf(fmaxf(a, p1), x2);
        float ss = exp2f((a - m3) * LOG2E) + exp2f((p1 - m3) * LOG2E) + exp2f((x2 - m3) * LOG2E);
        float a63 = rdlane(a, 63);
        float eb  = rdlane(ev, 0);
        float m2 = fmaxf(a64, a63);
        a64 = m2 + log2f(exp2f((a64 - m2) * LOG2E) + exp2f((a63 - m2) * LOG2E)) * LN2 + eb;
        a = m3 + log2f(ss) * LN2 + ev;
    };
    loadChunk(pvA, 0);
    loadChunk(pvB, 1);
    a = (s < 2) ? pvA[0] : NEGV;
#pragma unroll
    for (int j = 1; j < CH; ++j) step(pvA[j]);
    for (int c = 1; c < NCH; c += 2) {
        if (c + 1 < NCH) loadChunk(pvA, c + 1);
#pragma unroll
        for (int j = 0; j < CH; ++j) step(pvB[j]);
        if (c + 1 < NCH) {
            if (c + 2 < NCH) loadChunk(pvB, c + 2);
#pragma unroll
            for (int j = 0; j < CH; ++j) step(pvA[j]);
        }
    }
    int idx = 2 * len;
    float vhi = (idx < 64) ? rdlane(a, idx) : a64;
    float vlo = rdlane(a, idx - 1);
    float mm = fmaxf(vhi, vlo);
    float lae = mm + log2f(exp2f((vhi - mm) * LOG2E) + exp2f((vlo - mm) * LOG2E)) * LN2;
    float loss = ksum - lae;
    if (lane == 0) {
        if (p < BB) lm[p] = loss;
        else        ls[p - BB] = loss;
    }
}

// ---------------------------------------------------------------------------
// Finalize scalar loss (separate kernel; no cross-XCD atomics).
// ---------------------------------------------------------------------------
__global__ __launch_bounds__(256) void fin_kernel(const float* __restrict__ lm,
                                                  const float* __restrict__ ls,
                                                  const int* __restrict__ length,
                                                  const int* __restrict__ slength,
                                                  float* __restrict__ out) {
    __shared__ float red[256];
    const int tid = threadIdx.x;

    float mterm = 0.f;
    if (tid < BB) mterm = lm[tid] / (float)length[tid];

    int bb = tid >> 2;
    float conf = expf(-lm[bb]);
    float r = 0.01f + 0.99f * (1.f - conf) * (1.f - conf);
    int sl = slength[tid]; if (sl < 1) sl = 1;
    float sterm = r * ls[tid] / (float)sl;

    red[tid] = mterm; __syncthreads();
    for (int off = 128; off; off >>= 1) {
        if (tid < off) red[tid] += red[tid + off];
        __syncthreads();
    }
    float sum_m = red[0];
    __syncthreads();

    red[tid] = sterm; __syncthreads();
    for (int off = 128; off; off >>= 1) {
        if (tid < off) red[tid] += red[tid + off];
        __syncthreads();
    }
    if (tid == 0)
        out[0] = sum_m / (float)BB + 0.1f * (red[0] / (float)(BB * COR));
}

// ---------------------------------------------------------------------------
extern "C" void kernel_launch(void* const* d_in, const int* in_sizes, int n_in,
                              void* d_out, int out_size, void* d_ws, size_t ws_size,
                              hipStream_t stream) {
    const float* preds   = (const float*)d_in[0];
    const int*   text    = (const int*)d_in[1];
    const int*   length  = (const int*)d_in[2];
    const int*   stext   = (const int*)d_in[3];
    const int*   slength = (const int*)d_in[4];
    float* out = (float*)d_out;

    size_t need = ((size_t)BB * TT + BB + BB * COR + (size_t)NPROB * TT * SS) * sizeof(float);

    if (ws_size >= need) {
        float* blankE = (float*)d_ws;            // 64*512
        float* lm     = blankE + BB * TT;        // 64
        float* ls     = lm + BB;                 // 256
        float* labels = ls + BB * COR;           // 320*512*32 fp32 (16B-aligned)

        // 32768 row-waves, 4 waves/block -> 8192 blocks (r10-proven geometry)
        gather_kernel<<<(BB * TT) / 4, 256, 0, stream>>>(preds, text, stext, labels, blankE);
        ctc_lin_kernel<<<NPROB, 64, 0, stream>>>(labels, blankE, text, length, stext, slength, lm, ls);
        fin_kernel<<<1, 256, 0, stream>>>(lm, ls, length, slength, out);
    } else {
        float* lse = (float*)d_ws;
        float* lm  = lse + BB * TT;
        float* ls  = lm + BB;
        lse_kernel<<<(BB * TT) / 4, 256, 0, stream>>>(preds, lse);
        ctc_kernel<<<NPROB, 64, 0, stream>>>(preds, lse, text, length, stext, slength, lm, ls);
        fin_kernel<<<1, 256, 0, stream>>>(lm, ls, length, slength, out);
    }
}

// Round 15
// 50.464 us; speedup vs baseline: 1.2726x; 1.2726x over previous
//
#include <hip/hip_runtime.h>
#include <cmath>

#define BB 64
#define TT 512
#define CC 1000
#define SS 32
#define COR 4
#define NPROB (BB + BB*COR)   // 320
#define NEGV (-1e30f)
#define LOG2E 1.4426950408889634f
#define LN2 0.6931471805599453f
#define BIAS 50               // renorm target exponent: needed-max -> 2^BIAS
#define SHIFT 16.0f           // constant lse shift (replaces wave max; |w|<=8)

// ---------------------------------------------------------------------------
// DPP helpers (VALU-pipe cross-lane). 0x138 = wave_shr:1 (HW-verified r3-r14).
// Reduction tree row_shr:1/2/4/8 + row_bcast:15/31 -> lane 63 (HW-verified).
// ---------------------------------------------------------------------------
__device__ __forceinline__ float dpp_shr1_fill(float x, float fill) {
    int r = __builtin_amdgcn_update_dpp(__builtin_bit_cast(int, fill),
                                        __builtin_bit_cast(int, x),
                                        0x138, 0xf, 0xf, false);   // lane0 <- fill
    return __builtin_bit_cast(float, r);
}
__device__ __forceinline__ float dpp_shr1_z(float x) {
    int r = __builtin_amdgcn_update_dpp(0, __builtin_bit_cast(int, x),
                                        0x138, 0xf, 0xf, true);    // lane0 <- 0
    return __builtin_bit_cast(float, r);
}
template<int CTRL>
__device__ __forceinline__ float dpp_maxf(float m) {   // 0-fill ok: A >= 0
    int r = __builtin_amdgcn_update_dpp(0, __builtin_bit_cast(int, m),
                                        CTRL, 0xf, 0xf, true);
    return fmaxf(m, __builtin_bit_cast(float, r));
}
template<int CTRL>
__device__ __forceinline__ float dpp_addf(float s) {
    int r = __builtin_amdgcn_update_dpp(0, __builtin_bit_cast(int, s),
                                        CTRL, 0xf, 0xf, true);     // invalid -> +0
    return s + __builtin_bit_cast(float, r);
}
__device__ __forceinline__ float rdlane(float x, int lane) {
    return __builtin_bit_cast(float, __builtin_amdgcn_readlane(__builtin_bit_cast(int, x), lane));
}
// exact full-wave sum, result broadcast via readlane 63
__device__ __forceinline__ float wave_sum(float s) {
    s = dpp_addf<0x111>(s);
    s = dpp_addf<0x112>(s);
    s = dpp_addf<0x114>(s);
    s = dpp_addf<0x118>(s);
    s = dpp_addf<0x142>(s);
    s = dpp_addf<0x143>(s);
    return rdlane(s, 63);
}

// Renorm vs max over NEEDED lanes (lane < nl), all-VALU (~40cy).
// Scales so needed-max exponent == BIAS; accumulates true exponent in off.
__device__ __forceinline__ void renorm(float &A, float &a0, int &off,
                                       int lane, int nl) {
    float m = (lane < nl) ? A : 0.f;
    m = dpp_maxf<0x111>(m);
    m = dpp_maxf<0x112>(m);
    m = dpp_maxf<0x114>(m);
    m = dpp_maxf<0x118>(m);
    m = dpp_maxf<0x142>(m);
    m = dpp_maxf<0x143>(m);
    int mb = __builtin_amdgcn_readlane(__builtin_bit_cast(int, m), 63);
    int e = ((mb >> 23) & 0xff) - 127 - BIAS;
    e = (mb & 0x7fffffff) ? e : 0;       // m==0 guard
    A  = ldexpf(A,  -e);
    a0 = ldexpf(a0, -e);
    off += e;
}

// ---------------------------------------------------------------------------
// Gather kernel (r15: label-gather loads hoisted ABOVE the reduction).
// The 160 row[cls] loads never depended on lse2 -- issuing them alongside the
// stream loads lets them complete during the reduce (L1-hot) instead of
// serially after it (L2/L3, ~300-500cy, row evicted by then). Arithmetic is
// bitwise identical to r13; only load order changes.
// lane g-slots: it0 g=lane (pp 0-1), it1 g=lane+64 (pp 2-3),
//               it2 g=lane+128 (pp 4, lanes<32 only).
// ---------------------------------------------------------------------------
__global__ __launch_bounds__(256) void gather_kernel(const float* __restrict__ preds,
                                                     const int* __restrict__ text,
                                                     const int* __restrict__ stext,
                                                     float* __restrict__ labels,
                                                     float* __restrict__ blankE) {
    int gw = (blockIdx.x * blockDim.x + threadIdx.x) >> 6;   // row = b*512+t
    int lane = threadIdx.x & 63;
    if (gw >= BB * TT) return;
    int b = gw >> 9;
    int t = gw & (TT - 1);
    const float* row = preds + (size_t)gw * CC;
    const float4* row4 = (const float4*)row;

    // ---- label class indices + EARLY gather loads (independent of lse2) ----
    const int k  = lane & 31;
    const int hi = lane >> 5;                // 0 or 1
    int cls0, pid0;
    if (hi == 0) { cls0 = text[b * SS + k];                pid0 = b; }
    else         { cls0 = stext[(b * COR + 0) * SS + k];   pid0 = BB + b * COR + 0; }
    const int i1 = b * COR + 1 + hi;         // pp=2 -> cor 1, pp=3 -> cor 2
    const int cls1 = stext[i1 * SS + k];
    const int pid1 = BB + i1;
    const bool has2 = (hi == 0);             // pp=4 handled by lanes 0..31
    const int i2 = b * COR + 3;
    const int cls2 = has2 ? stext[i2 * SS + k] : 0;   // cls2=0 -> row[0], valid
    const int pid2 = BB + i2;

    float v0 = row[cls0];
    float v1 = row[cls1];
    float v2 = row[cls2];

    // ---- stream + constant-shift exp2 partial sums ----
    float s = 0.f;
#pragma unroll
    for (int i = 0; i < 4; ++i) {
        int idx = lane + i * 64;
        float4 x = (idx < 250) ? row4[idx] : make_float4(NEGV, NEGV, NEGV, NEGV);
        s += exp2f(fmaf(x.x, LOG2E, -SHIFT));
        s += exp2f(fmaf(x.y, LOG2E, -SHIFT));
        s += exp2f(fmaf(x.z, LOG2E, -SHIFT));
        s += exp2f(fmaf(x.w, LOG2E, -SHIFT));
    }
    s = wave_sum(s);
    float lse2 = SHIFT + log2f(s);           // wave-uniform log2(sum exp2)

    if (lane == 0) blankE[gw] = exp2f(fmaf(row[0], LOG2E, -lse2));

    // ---- scale + scatter (gathered values already in registers) ----
    labels[((size_t)pid0 * TT + t) * SS + k] = exp2f(fmaf(v0, LOG2E, -lse2));
    labels[((size_t)pid1 * TT + t) * SS + k] = exp2f(fmaf(v1, LOG2E, -lse2));
    if (has2)
        labels[((size_t)pid2 * TT + t) * SS + k] = exp2f(fmaf(v2, LOG2E, -lse2));
}

// ---------------------------------------------------------------------------
// Linear-domain CTC (r13-proven, byte-identical). Lane s owns extended
// position s+1; position 0 (leading blank) is the wave-uniform scalar a0
// (DPP fill operand). Per-step: dpp, dpp, cndmask x2, add, add, mul.
// CH=32 prefetch covers ~600cy L3 latency. Renorm every 8 steps, BIAS=50.
// loss = -ln2 * (log2(A[2len-1] + A[2len-2]) + off)  (emits pre-normalized).
// ---------------------------------------------------------------------------
__global__ __launch_bounds__(64) void ctc_lin_kernel(const float* __restrict__ labels,
                                                     const float* __restrict__ blankE,
                                                     const int* __restrict__ text,
                                                     const int* __restrict__ length,
                                                     const int* __restrict__ stext,
                                                     const int* __restrict__ slength,
                                                     float* __restrict__ lm,
                                                     float* __restrict__ ls) {
    const int p = blockIdx.x;
    const int lane = threadIdx.x;

    int b, len;
    const int* tgt;
    if (p < BB) { b = p;        tgt = text  + (size_t)p * SS; len = length[p]; }
    else { int i = p - BB; b = i / COR; tgt = stext + (size_t)i * SS; len = slength[i]; }

    const bool evenl = !(lane & 1);
    const int k = lane >> 1;
    bool use2 = false;
    if (evenl && lane >= 2) use2 = (tgt[k] != tgt[k - 1]);

    const float* bbase = blankE + (size_t)b * TT;
    const float* lbase = labels + (size_t)p * TT * SS + k;     // even lanes
    const int i2 = 2 * len;                  // needed lanes: [0, i2)

    constexpr int CH = 32;
    constexpr int NCH = TT / CH;             // 16
    float eA[CH], eB[CH], bA[CH], bB[CH];

    auto loadChunk = [&](float (&ee)[CH], float (&bv)[CH], int c) {
        if (evenl) {
#pragma unroll
            for (int j = 0; j < CH; ++j)
                ee[j] = lbase[(size_t)(c * CH + j) * SS];
        }
        const float4* b4 = (const float4*)(bbase + c * CH);
#pragma unroll
        for (int q = 0; q < CH / 4; ++q) {
            float4 y = b4[q];
            bv[q*4+0] = y.x; bv[q*4+1] = y.y; bv[q*4+2] = y.z; bv[q*4+3] = y.w;
        }
    };

    float A, a0;
    int off = 0;

#define RUNCH(EE, BV, START)                                    \
    _Pragma("unroll")                                           \
    for (int j = (START); j < CH; ++j) {                        \
        float ev = evenl ? EE[j] : BV[j];                       \
        float p1 = dpp_shr1_fill(A, a0);                        \
        float p2 = dpp_shr1_z(p1);                              \
        float x2 = use2 ? p2 : 0.f;                             \
        A = (A + p1 + x2) * ev;                                 \
        a0 *= BV[j];                                            \
        if ((j & 7) == 7) renorm(A, a0, off, lane, i2);         \
    }

    // prologue: chunk 0 (t=0 is init), chunk 1 prefetched
    loadChunk(eA, bA, 0);
    loadChunk(eB, bB, 1);
    A  = (lane == 0) ? eA[0] : 0.f;          // alpha0[pos1] = emit(y1); lane0 even
    a0 = bA[0];                              // alpha0[pos0] = emit(blank)
    RUNCH(eA, bA, 1)

    for (int c = 1; c < NCH; c += 2) {
        if (c + 1 < NCH) loadChunk(eA, bA, c + 1);
        RUNCH(eB, bB, 0)
        if (c + 1 < NCH) {
            if (c + 2 < NCH) loadChunk(eB, bB, c + 2);
            RUNCH(eA, bA, 0)
        }
    }
#undef RUNCH

    // final: alpha[2len] at lane 2len-1, alpha[2len-1] at lane 2len-2
    float vhi = rdlane(A, i2 - 1);
    float vlo = rdlane(A, i2 - 2);
    float loss = -LN2 * (log2f(vhi + vlo) + (float)off);

    if (lane == 0) {
        if (p < BB) lm[p] = loss;
        else        ls[p - BB] = loss;
    }
}

// ---------------------------------------------------------------------------
// Fallback path (only if ws too small) — round-3 log-domain kernels (proven).
// ---------------------------------------------------------------------------
__global__ __launch_bounds__(256) void lse_kernel(const float* __restrict__ preds,
                                                  float* __restrict__ lse) {
    int wave = (blockIdx.x * blockDim.x + threadIdx.x) >> 6;
    int lane = threadIdx.x & 63;
    if (wave >= BB * TT) return;
    const float4* row = (const float4*)(preds + (size_t)wave * CC);
    float v[16];
#pragma unroll
    for (int i = 0; i < 4; ++i) {
        int idx = lane + i * 64;
        float4 x = (idx < 250) ? row[idx] : make_float4(NEGV, NEGV, NEGV, NEGV);
        v[i*4+0] = x.x; v[i*4+1] = x.y; v[i*4+2] = x.z; v[i*4+3] = x.w;
    }
    float m = v[0];
#pragma unroll
    for (int i = 1; i < 16; ++i) m = fmaxf(m, v[i]);
#pragma unroll
    for (int off = 32; off; off >>= 1) m = fmaxf(m, __shfl_xor(m, off));
    float s = 0.f;
#pragma unroll
    for (int i = 0; i < 16; ++i) s += exp2f((v[i] - m) * LOG2E);
#pragma unroll
    for (int off = 32; off; off >>= 1) s += __shfl_xor(s, off);
    if (lane == 0) lse[wave] = m + log2f(s) * LN2;
}

__global__ __launch_bounds__(64) void ctc_kernel(const float* __restrict__ preds,
                                                 const float* __restrict__ lse,
                                                 const int* __restrict__ text,
                                                 const int* __restrict__ length,
                                                 const int* __restrict__ stext,
                                                 const int* __restrict__ slength,
                                                 float* __restrict__ lm,
                                                 float* __restrict__ ls) {
    const int p = blockIdx.x;
    const int lane = threadIdx.x;
    int b, len;
    const int* tgt;
    if (p < BB) { b = p;        tgt = text  + (size_t)p * SS; len = length[p]; }
    else { int i = p - BB; b = i / COR; tgt = stext + (size_t)i * SS; len = slength[i]; }
    const int s = lane;
    int cls = (s & 1) ? tgt[(s - 1) >> 1] : 0;
    bool use2 = false;
    if ((s & 1) && s >= 3) use2 = (cls != tgt[(s - 3) >> 1]);
    const float* pcls = preds + (size_t)b * TT * CC + cls;
    const float* lrow = lse + (size_t)b * TT;
    float ksum = 0.f;
#pragma unroll
    for (int i = 0; i < TT / 64; ++i) ksum += lrow[lane + i * 64];
#pragma unroll
    for (int off = 32; off; off >>= 1) ksum += __shfl_xor(ksum, off);
    float a, a64 = NEGV;
    constexpr int CH = 8;
    constexpr int NCH = TT / CH;
    float pvA[CH], pvB[CH];
    auto loadChunk = [&](float (&pv)[CH], int c) {
#pragma unroll
        for (int j = 0; j < CH; ++j) pv[j] = pcls[(size_t)(c * CH + j) * CC];
    };
    auto step = [&](float ev) {
        float p1 = dpp_shr1_fill(a, NEGV);
        float p2 = dpp_shr1_fill(p1, NEGV);
        float x2 = use2 ? p2 : NEGV;
        float m3 = fmaxf(fmaxf(a, p1), x2);
        float ss = exp2f((a - m3) * LOG2E) + exp2f((p1 - m3) * LOG2E) + exp2f((x2 - m3) * LOG2E);
        float a63 = rdlane(a, 63);
        float eb  = rdlane(ev, 0);
        float m2 = fmaxf(a64, a63);
        a64 = m2 + log2f(exp2f((a64 - m2) * LOG2E) + exp2f((a63 - m2) * LOG2E)) * LN2 + eb;
        a = m3 + log2f(ss) * LN2 + ev;
    };
    loadChunk(pvA, 0);
    loadChunk(pvB, 1);
    a = (s < 2) ? pvA[0] : NEGV;
#pragma unroll
    for (int j = 1; j < CH; ++j) step(pvA[j]);
    for (int c = 1; c < NCH; c += 2) {
        if (c + 1 < NCH) loadChunk(pvA, c + 1);
#pragma unroll
        for (int j = 0; j < CH; ++j) step(pvB[j]);
        if (c + 1 < NCH) {
            if (c + 2 < NCH) loadChunk(pvB, c + 2);
#pragma unroll
            for (int j = 0; j < CH; ++j) step(pvA[j]);
        }
    }
    int idx = 2 * len;
    float vhi = (idx < 64) ? rdlane(a, idx) : a64;
    float vlo = rdlane(a, idx - 1);
    float mm = fmaxf(vhi, vlo);
    float lae = mm + log2f(exp2f((vhi - mm) * LOG2E) + exp2f((vlo - mm) * LOG2E)) * LN2;
    float loss = ksum - lae;
    if (lane == 0) {
        if (p < BB) lm[p] = loss;
        else        ls[p - BB] = loss;
    }
}

// ---------------------------------------------------------------------------
// Finalize scalar loss (separate kernel; no cross-XCD atomics).
// ---------------------------------------------------------------------------
__global__ __launch_bounds__(256) void fin_kernel(const float* __restrict__ lm,
                                                  const float* __restrict__ ls,
                                                  const int* __restrict__ length,
                                                  const int* __restrict__ slength,
                                                  float* __restrict__ out) {
    __shared__ float red[256];
    const int tid = threadIdx.x;

    float mterm = 0.f;
    if (tid < BB) mterm = lm[tid] / (float)length[tid];

    int bb = tid >> 2;
    float conf = expf(-lm[bb]);
    float r = 0.01f + 0.99f * (1.f - conf) * (1.f - conf);
    int sl = slength[tid]; if (sl < 1) sl = 1;
    float sterm = r * ls[tid] / (float)sl;

    red[tid] = mterm; __syncthreads();
    for (int off = 128; off; off >>= 1) {
        if (tid < off) red[tid] += red[tid + off];
        __syncthreads();
    }
    float sum_m = red[0];
    __syncthreads();

    red[tid] = sterm; __syncthreads();
    for (int off = 128; off; off >>= 1) {
        if (tid < off) red[tid] += red[tid + off];
        __syncthreads();
    }
    if (tid == 0)
        out[0] = sum_m / (float)BB + 0.1f * (red[0] / (float)(BB * COR));
}

// ---------------------------------------------------------------------------
extern "C" void kernel_launch(void* const* d_in, const int* in_sizes, int n_in,
                              void* d_out, int out_size, void* d_ws, size_t ws_size,
                              hipStream_t stream) {
    const float* preds   = (const float*)d_in[0];
    const int*   text    = (const int*)d_in[1];
    const int*   length  = (const int*)d_in[2];
    const int*   stext   = (const int*)d_in[3];
    const int*   slength = (const int*)d_in[4];
    float* out = (float*)d_out;

    size_t need = ((size_t)BB * TT + BB + BB * COR + (size_t)NPROB * TT * SS) * sizeof(float);

    if (ws_size >= need) {
        float* blankE = (float*)d_ws;            // 64*512
        float* lm     = blankE + BB * TT;        // 64
        float* ls     = lm + BB;                 // 256
        float* labels = ls + BB * COR;           // 320*512*32 fp32 (16B-aligned)

        // 32768 row-waves, 4 waves/block -> 8192 blocks (r10-proven geometry)
        gather_kernel<<<(BB * TT) / 4, 256, 0, stream>>>(preds, text, stext, labels, blankE);
        ctc_lin_kernel<<<NPROB, 64, 0, stream>>>(labels, blankE, text, length, stext, slength, lm, ls);
        fin_kernel<<<1, 256, 0, stream>>>(lm, ls, length, slength, out);
    } else {
        float* lse = (float*)d_ws;
        float* lm  = lse + BB * TT;
        float* ls  = lm + BB;
        lse_kernel<<<(BB * TT) / 4, 256, 0, stream>>>(preds, lse);
        ctc_kernel<<<NPROB, 64, 0, stream>>>(preds, lse, text, length, stext, slength, lm, ls);
        fin_kernel<<<1, 256, 0, stream>>>(lm, ls, length, slength, out);
    }
}